// Round 6
// baseline (253.009 us; speedup 1.0000x reference)
//
#include <hip/hip_runtime.h>
#include <stdint.h>
#include <math.h>

typedef unsigned short u16;
typedef __bf16 bf16x8 __attribute__((ext_vector_type(8)));
typedef float f32x4 __attribute__((ext_vector_type(4)));

enum { M_QKV = 0, M_SCORE = 1, M_PV = 2 };

// fp32 -> bf16 round-to-nearest-even, bit-level
__device__ __forceinline__ u16 f2bf(float f) {
    union { float f; unsigned int u; } a; a.f = f;
    unsigned int u = a.u;
    u += 0x7FFFu + ((u >> 16) & 1u);
    return (u16)(u >> 16);
}

__device__ __forceinline__ void async_load16(const void* g, void* l) {
    __builtin_amdgcn_global_load_lds(
        (const __attribute__((address_space(1))) void*)g,
        (__attribute__((address_space(3))) void*)l,
        16, 0, 0);
}

// ---------------------------------------------------------------------------
// C[M,N] = A[M,K] * Bt[N,K]^T (bf16 in, fp32 acc). 128x128 tile, 4 waves 2x2,
// each wave 64x64 (4x4 16x16x32 frags x KB/32 k-halves).
// KB = K-depth staged per iteration (64 -> 32 KB LDS, 128 -> 64 KB LDS).
// LDS row = KB elems = GR 16B granules; granule (row,g) stored at slot
// g ^ (row & (GR-1)). Staging permutes the *global* granule per lane (the LDS
// side of global_load_lds is fixed wave-uniform-base + lane*16). Fragment
// ds_read_b128: within any 16-lane phase the physical slots are a permutation
// -> <=2 granules per bank-octet (R3/R5 verified this family: 0 conflicts).
//
// M_QKV : bn 0-7 -> Q, 8-15 -> K, 16-23 -> V, all row-major [B*T, 1024].
// M_SCORE: grid.x = linear lower-tri 128x128 block index; epilogue writes
//          E = exp2(acc*kfac) bf16 (causal-masked) + atomic per-row sum-of-exp.
// M_PV  : K-loop limited to causal extent (bm+1)*128; scales by 1/rowsum.
// ---------------------------------------------------------------------------
template<int MODE, int KB>
__global__ __launch_bounds__(256)
void gemm_bt(const u16* __restrict__ A, long long sAb,
             const u16* __restrict__ Bt, long long sBb,
             void* __restrict__ Cv, long long sCb,
             float* __restrict__ rowsum,
             int M, int N, int K, float kfac)
{
    constexpr int GR  = KB / 8;            // 16B granules per LDS row (8 or 16)
    constexpr int RPC = 64 / GR;           // rows per 1KB staging chunk (8 or 4)
    constexpr int CPW = (128 / RPC) / 4;   // chunks per wave (4 or 8)
    constexpr int KH  = KB / 32;           // MFMA k-steps per iteration (2 or 4)

    int bm, bn;
    if (MODE == M_SCORE) {
        const int idx = blockIdx.x;
        bm = (int)((sqrtf(8.f * idx + 1.f) - 1.f) * 0.5f);
        while ((bm + 1) * (bm + 2) / 2 <= idx) ++bm;
        while (bm * (bm + 1) / 2 > idx) --bm;
        bn = idx - bm * (bm + 1) / 2;
    } else {
        bn = blockIdx.x; bm = blockIdx.y;
    }
    const int bz = blockIdx.z;
    A  += (size_t)bz * sAb;
    Bt += (size_t)bz * sBb;

    const int tid  = threadIdx.x;
    const int lane = tid & 63;
    const int wv   = tid >> 6;
    const int wm   = wv >> 1;         // wave row (0..1)
    const int wn   = wv & 1;          // wave col (0..1)

    __shared__ __attribute__((aligned(16))) u16 As[128 * KB];
    __shared__ __attribute__((aligned(16))) u16 Bs[128 * KB];

    f32x4 acc[4][4] = {};

    const int rowA0 = bm * 128, rowB0 = bn * 128;
    // staging decomposition of lane -> (row-in-chunk, physical slot)
    const int lrow  = lane / GR;
    const int lslot = lane & (GR - 1);

    int kEnd = K;
    if (MODE == M_PV) { int ke = (bm + 1) * 128; kEnd = ke < K ? ke : K; }

    const int lm   = lane & 15;
    const int quad = lane >> 4;
    const int rx   = lm & (GR - 1);   // fragment-row xor (frag row bases % GR == 0... base rows are multiples of 16 >= GR)

    for (int k0 = 0; k0 < kEnd; k0 += KB) {
        #pragma unroll
        for (int c = 0; c < CPW; ++c) {
            const int cc  = wv * CPW + c;
            const int row = cc * RPC + lrow;
            const int g   = lslot ^ (row & (GR - 1));
            async_load16(&A[(size_t)(rowA0 + row) * K + k0 + g * 8], &As[cc * 512 + lane * 8]);
        }
        #pragma unroll
        for (int c = 0; c < CPW; ++c) {
            const int cc  = wv * CPW + c;
            const int row = cc * RPC + lrow;
            const int g   = lslot ^ (row & (GR - 1));
            async_load16(&Bt[(size_t)(rowB0 + row) * K + k0 + g * 8], &Bs[cc * 512 + lane * 8]);
        }
        __syncthreads();

        #pragma unroll
        for (int h = 0; h < KH; ++h) {
            bf16x8 af[4], bfr[4];
            #pragma unroll
            for (int i = 0; i < 4; ++i)
                af[i] = *reinterpret_cast<const bf16x8*>(
                    &As[(wm * 64 + i * 16 + lm) * KB + (((h * 4 + quad) ^ rx) * 8)]);
            #pragma unroll
            for (int j = 0; j < 4; ++j)
                bfr[j] = *reinterpret_cast<const bf16x8*>(
                    &Bs[(wn * 64 + j * 16 + lm) * KB + (((h * 4 + quad) ^ rx) * 8)]);
            #pragma unroll
            for (int i = 0; i < 4; ++i)
                #pragma unroll
                for (int j = 0; j < 4; ++j)
                    acc[i][j] = __builtin_amdgcn_mfma_f32_16x16x32_bf16(af[i], bfr[j], acc[i][j], 0, 0, 0);
        }
        __syncthreads();
    }

    // Epilogue. C/D layout (m89-verified): col = lane&15, row = quad*4 + reg.
    if (MODE == M_QKV) {
        u16* C = (u16*)Cv + (size_t)(bn >> 3) * sCb;  // 0-7:Q, 8-15:K, 16-23:V
        #pragma unroll
        for (int i = 0; i < 4; ++i)
            #pragma unroll
            for (int j = 0; j < 4; ++j) {
                const int r0 = rowA0 + wm * 64 + i * 16 + quad * 4;
                const int c0 = (rowB0 + wn * 64 + j * 16 + lm) & 1023;
                #pragma unroll
                for (int g = 0; g < 4; ++g)
                    C[(size_t)(r0 + g) * 1024 + c0] = f2bf(acc[i][j][g]);
            }
    } else if (MODE == M_SCORE) {
        u16* E = (u16*)Cv + (size_t)bz * sCb;
        float rs[4][4];
        #pragma unroll
        for (int i = 0; i < 4; ++i)
            #pragma unroll
            for (int g = 0; g < 4; ++g) rs[i][g] = 0.f;
        #pragma unroll
        for (int i = 0; i < 4; ++i)
            #pragma unroll
            for (int j = 0; j < 4; ++j) {
                const int r0 = rowA0 + wm * 64 + i * 16 + quad * 4;
                const int c  = rowB0 + wn * 64 + j * 16 + lm;
                #pragma unroll
                for (int g = 0; g < 4; ++g) {
                    const int r = r0 + g;
                    float e = (c <= r) ? exp2f(acc[i][j][g] * kfac) : 0.f;
                    E[(size_t)r * N + c] = f2bf(e);
                    rs[i][g] += e;
                }
            }
        #pragma unroll
        for (int i = 0; i < 4; ++i)
            #pragma unroll
            for (int g = 0; g < 4; ++g) {
                float v = rs[i][g];
                v += __shfl_xor(v, 1); v += __shfl_xor(v, 2);
                v += __shfl_xor(v, 4); v += __shfl_xor(v, 8);
                rs[i][g] = v;
            }
        if (lm == 0) {
            #pragma unroll
            for (int i = 0; i < 4; ++i)
                #pragma unroll
                for (int g = 0; g < 4; ++g) {
                    const int r = rowA0 + wm * 64 + i * 16 + quad * 4 + g;
                    atomicAdd(&rowsum[(size_t)bz * M + r], rs[i][g]);
                }
        }
    } else {  // M_PV
        float* C = (float*)Cv + (size_t)bz * sCb;
        #pragma unroll
        for (int i = 0; i < 4; ++i) {
            const int r0 = rowA0 + wm * 64 + i * 16 + quad * 4;
            float inv[4];
            #pragma unroll
            for (int g = 0; g < 4; ++g)
                inv[g] = 1.f / rowsum[(size_t)bz * M + r0 + g];
            #pragma unroll
            for (int j = 0; j < 4; ++j) {
                const int c0 = rowB0 + wn * 64 + j * 16 + lm;
                #pragma unroll
                for (int g = 0; g < 4; ++g)
                    C[(size_t)(r0 + g) * N + c0] = acc[i][j][g] * inv[g];
            }
        }
    }
}

// x fp32 -> bf16, 8 elems/thread
__global__ __launch_bounds__(256)
void cast_x(const float* __restrict__ x, u16* __restrict__ o, long long n)
{
    long long i = ((long long)blockIdx.x * blockDim.x + threadIdx.x) * 8;
    if (i >= n) return;
    const float4 a = *(const float4*)(x + i);
    const float4 b = *(const float4*)(x + i + 4);
    union { u16 u[8]; float4 v; } r;
    r.u[0] = f2bf(a.x); r.u[1] = f2bf(a.y); r.u[2] = f2bf(a.z); r.u[3] = f2bf(a.w);
    r.u[4] = f2bf(b.x); r.u[5] = f2bf(b.y); r.u[6] = f2bf(b.z); r.u[7] = f2bf(b.w);
    *(float4*)(o + i) = r.v;
}

// W[z][D][D] fp32 -> Wt[z][D][D] bf16 transposed; z selects Wq/Wk/Wv
__global__ __launch_bounds__(256)
void castT_w3(const float* __restrict__ W0, const float* __restrict__ W1,
              const float* __restrict__ W2, u16* __restrict__ Wt, int D)
{
    const float* W = blockIdx.z == 0 ? W0 : (blockIdx.z == 1 ? W1 : W2);
    u16* dst = Wt + (size_t)blockIdx.z * D * D;
    __shared__ u16 t[32][33];
    const int c0 = blockIdx.x * 32, r0 = blockIdx.y * 32;
    const int tx = threadIdx.x & 31, ty = threadIdx.x >> 5;  // ty 0..7
    #pragma unroll
    for (int s = 0; s < 32; s += 8)
        t[ty + s][tx] = f2bf(W[(size_t)(r0 + ty + s) * D + c0 + tx]);
    __syncthreads();
    #pragma unroll
    for (int s = 0; s < 32; s += 8)
        dst[(size_t)(c0 + ty + s) * D + r0 + tx] = t[tx][ty + s];
}

// V[rows][cols] bf16 -> Vt[cols][rows] bf16, batched via blockIdx.z
__global__ __launch_bounds__(256)
void transpose_b(const u16* __restrict__ V, long long sVb,
                 u16* __restrict__ Vt, long long sVtb, int rows, int cols)
{
    V  += (size_t)blockIdx.z * sVb;
    Vt += (size_t)blockIdx.z * sVtb;
    __shared__ u16 t[32][33];
    const int c0 = blockIdx.x * 32, r0 = blockIdx.y * 32;
    const int tx = threadIdx.x & 31, ty = threadIdx.x >> 5;
    #pragma unroll
    for (int s = 0; s < 32; s += 8)
        t[ty + s][tx] = V[(size_t)(r0 + ty + s) * cols + c0 + tx];
    __syncthreads();
    #pragma unroll
    for (int s = 0; s < 32; s += 8)
        Vt[(size_t)(c0 + ty + s) * rows + r0 + tx] = t[tx][ty + s];
}

extern "C" void kernel_launch(void* const* d_in, const int* in_sizes, int n_in,
                              void* d_out, int out_size, void* d_ws, size_t ws_size,
                              hipStream_t stream)
{
    const int B = 4, T = 2048, D = 1024;
    const float* x  = (const float*)d_in[0];
    const float* Wq = (const float*)d_in[1];
    const float* Wk = (const float*)d_in[2];
    const float* Wv = (const float*)d_in[3];
    float* out = (float*)d_out;

    const size_t nX = (size_t)B * T * D;
    u16* Xb = (u16*)d_ws;                          // [B*T, D] bf16
    u16* Wt = Xb + nX;                             // 3 x [D, D] bf16 transposed
    u16* Q  = Wt + 3 * (size_t)D * D;              // [B*T, D]  (Q,K,V contiguous)
    u16* Kb = Q + nX;
    u16* Vb = Kb + nX;
    u16* Vt = Vb + nX;                             // [B][D][T]
    char* rest = (char*)(Vt + nX);
    const size_t fixed   = (size_t)((char*)rest - (char*)d_ws);
    const size_t perb_E  = (size_t)T * T * 2;
    const size_t perb_rs = (size_t)T * 4;
    const bool full = ws_size >= fixed + (size_t)B * (perb_E + perb_rs);
    const int nb = full ? B : 1;
    u16*   E  = (u16*)rest;
    float* RS = (float*)(E + nb * (size_t)T * T);

    const float kfac = 1.4426950408889634f / 32.0f;  // log2(e)/sqrt(d_out)
    const int nTri = (T / 128) * (T / 128 + 1) / 2;  // 136 causal 128x128 blocks

    // 1. casts
    cast_x<<<dim3((unsigned)(nX / (8 * 256))), 256, 0, stream>>>(x, Xb, (long long)nX);
    castT_w3<<<dim3(D / 32, D / 32, 3), 256, 0, stream>>>(Wq, Wk, Wv, Wt, D);

    // 2. Merged QKV projection (KB=64: 5 blocks/CU residency, measured 805 TF)
    gemm_bt<M_QKV, 64><<<dim3(3 * D / 128, (B * T) / 128, 1), 256, 0, stream>>>(
        Xb, 0, Wt, 0, Q, (long long)nX, nullptr, B * T, 3 * D, D, 0.f);

    if (full) {
        hipMemsetAsync(RS, 0, (size_t)B * T * 4, stream);
        // 3. E = exp2(kfac * Q K^T) bf16 (causal) + rowsum. KB=128: the grid
        // (544 blocks) caps residency at ~2/CU anyway, so 64 KB LDS is free
        // and halves the number of barrier drains (16 -> 8 iters).
        gemm_bt<M_SCORE, 128><<<dim3(nTri, 1, B), 256, 0, stream>>>(
            Q, (long long)T * D, Kb, (long long)T * D, E, (long long)T * T, RS,
            T, T, D, kfac);
        // 4. V^T
        transpose_b<<<dim3(D / 32, T / 32, B), 256, 0, stream>>>(
            Vb, (long long)T * D, Vt, (long long)D * T, T, D);
        // 5. O = (E Vt^T) / rowsum; K-loop to causal extent (KB=128, same logic)
        gemm_bt<M_PV, 128><<<dim3(D / 128, T / 128, B), 256, 0, stream>>>(
            E, (long long)T * T, Vt, (long long)D * T, out, (long long)T * D, RS,
            T, D, T, 0.f);
    } else {
        for (int b = 0; b < B; ++b) {
            const size_t ob = (size_t)b * T * D;
            hipMemsetAsync(RS, 0, (size_t)T * 4, stream);
            gemm_bt<M_SCORE, 128><<<dim3(nTri, 1, 1), 256, 0, stream>>>(
                Q + ob, 0, Kb + ob, 0, E, 0, RS, T, T, D, kfac);
            transpose_b<<<dim3(D / 32, T / 32, 1), 256, 0, stream>>>(
                Vb + ob, 0, Vt, 0, T, D);
            gemm_bt<M_PV, 128><<<dim3(D / 128, T / 128, 1), 256, 0, stream>>>(
                E, 0, Vt, 0, out + ob, 0, RS, T, D, T, 0.f);
        }
    }
}

// Round 7
// 247.364 us; speedup vs baseline: 1.0228x; 1.0228x over previous
//
#include <hip/hip_runtime.h>
#include <stdint.h>
#include <math.h>

typedef unsigned short u16;
typedef __bf16 bf16x8 __attribute__((ext_vector_type(8)));
typedef float f32x4 __attribute__((ext_vector_type(4)));

enum { M_QKV = 0, M_SCORE = 1, M_PV = 2 };

// fp32 -> bf16 round-to-nearest-even, bit-level
__device__ __forceinline__ u16 f2bf(float f) {
    union { float f; unsigned int u; } a; a.f = f;
    unsigned int u = a.u;
    u += 0x7FFFu + ((u >> 16) & 1u);
    return (u16)(u >> 16);
}

__device__ __forceinline__ void async_load16(const void* g, void* l) {
    __builtin_amdgcn_global_load_lds(
        (const __attribute__((address_space(1))) void*)g,
        (__attribute__((address_space(3))) void*)l,
        16, 0, 0);
}

// ---------------------------------------------------------------------------
// C[M,N] = A[M,K] * Bt[N,K]^T (bf16 in, fp32 acc). TBM x 128 tile, KB=64
// staged per iteration, 4 waves 2x2 (each wave TBM/2 x 64).
// LDS row = 64 elems = 8 x 16B granules; granule (row,g) at slot g^(row&7);
// staging permutes the global granule per lane (LDS side of global_load_lds
// stays lane-linear). R3/R5 verified: 0 bank conflicts, QKV 805 TF.
//
// M_QKV  (TBM=128): bn 0-7 -> Q, 8-15 -> K, 16-23 -> V, row-major [B*T,1024].
// M_SCORE(TBM=64): grid.x = linear lower-tri index over 64x128 blocks
//          (row-tile bm has bm/2+1 col-tiles, 272 total); epilogue writes
//          E = exp2(acc*kfac) bf16 causal-masked + atomic per-row sum-of-exp.
// M_PV   (TBM=64): K-loop to causal extent (bm+1)*TBM; scales by 1/rowsum.
// ---------------------------------------------------------------------------
template<int MODE, int TBM>
__global__ __launch_bounds__(256)
void gemm_bt(const u16* __restrict__ A, long long sAb,
             const u16* __restrict__ Bt, long long sBb,
             void* __restrict__ Cv, long long sCb,
             float* __restrict__ rowsum,
             int M, int N, int K, float kfac)
{
    constexpr int KB  = 64;
    constexpr int NI  = TBM / 32;        // m-frags per wave (2 or 4)
    constexpr int ACH = TBM / 32;        // A staging chunks per wave (2 or 4)
    constexpr int BCH = 4;               // B staging chunks per wave (TBN=128)

    int bm, bn;
    if (MODE == M_SCORE) {
        // 64-row tri decode (verified R4): w = floor(sqrt(idx))
        const int idx = blockIdx.x;
        int w = (int)sqrtf((float)idx + 0.5f);
        while (w * w > idx) --w;
        while ((w + 1) * (w + 1) <= idx) ++w;
        if (idx < w * w + w) { bm = 2 * w - 1; bn = idx - w * w; }
        else                 { bm = 2 * w;     bn = idx - (w * w + w); }
    } else {
        bn = blockIdx.x; bm = blockIdx.y;
    }
    const int bz = blockIdx.z;
    A  += (size_t)bz * sAb;
    Bt += (size_t)bz * sBb;

    const int tid  = threadIdx.x;
    const int lane = tid & 63;
    const int wv   = tid >> 6;
    const int wm   = wv >> 1;         // wave row (0..1)
    const int wn   = wv & 1;          // wave col (0..1)

    __shared__ __attribute__((aligned(16))) u16 As[TBM * KB];
    __shared__ __attribute__((aligned(16))) u16 Bs[128 * KB];

    f32x4 acc[NI][4] = {};

    const int rowA0 = bm * TBM, rowB0 = bn * 128;
    // staging: chunk = 8 rows x 8 granules (1 KB); lane -> (row lane/8, slot lane&7)
    const int lrow  = lane >> 3;
    const int lslot = lane & 7;
    const int sg    = (lslot ^ lrow) * 8;   // global column granule offset (elems)

    int kEnd = K;
    if (MODE == M_PV) { int ke = (bm + 1) * TBM; kEnd = ke < K ? ke : K; }

    const int lm   = lane & 15;
    const int quad = lane >> 4;
    const int rx   = lm & 7;          // fragment-row xor

    for (int k0 = 0; k0 < kEnd; k0 += KB) {
        #pragma unroll
        for (int c = 0; c < ACH; ++c) {
            const int cc  = wv * ACH + c;
            const int row = cc * 8 + lrow;
            async_load16(&A[(size_t)(rowA0 + row) * K + k0 + sg], &As[cc * 512 + lane * 8]);
        }
        #pragma unroll
        for (int c = 0; c < BCH; ++c) {
            const int cc  = wv * BCH + c;
            const int row = cc * 8 + lrow;
            async_load16(&Bt[(size_t)(rowB0 + row) * K + k0 + sg], &Bs[cc * 512 + lane * 8]);
        }
        __syncthreads();

        #pragma unroll
        for (int h = 0; h < 2; ++h) {
            const int sl = (((h * 4 + quad) ^ rx) * 8);
            bf16x8 af[NI], bfr[4];
            #pragma unroll
            for (int i = 0; i < NI; ++i)
                af[i] = *reinterpret_cast<const bf16x8*>(
                    &As[(wm * (TBM / 2) + i * 16 + lm) * KB + sl]);
            #pragma unroll
            for (int j = 0; j < 4; ++j)
                bfr[j] = *reinterpret_cast<const bf16x8*>(
                    &Bs[(wn * 64 + j * 16 + lm) * KB + sl]);
            #pragma unroll
            for (int i = 0; i < NI; ++i)
                #pragma unroll
                for (int j = 0; j < 4; ++j)
                    acc[i][j] = __builtin_amdgcn_mfma_f32_16x16x32_bf16(af[i], bfr[j], acc[i][j], 0, 0, 0);
        }
        __syncthreads();
    }

    // Epilogue. C/D layout (m89-verified): col = lane&15, row = quad*4 + reg.
    if (MODE == M_QKV) {
        u16* C = (u16*)Cv + (size_t)(bn >> 3) * sCb;  // 0-7:Q, 8-15:K, 16-23:V
        #pragma unroll
        for (int i = 0; i < NI; ++i)
            #pragma unroll
            for (int j = 0; j < 4; ++j) {
                const int r0 = rowA0 + wm * (TBM / 2) + i * 16 + quad * 4;
                const int c0 = (rowB0 + wn * 64 + j * 16 + lm) & 1023;
                #pragma unroll
                for (int g = 0; g < 4; ++g)
                    C[(size_t)(r0 + g) * 1024 + c0] = f2bf(acc[i][j][g]);
            }
    } else if (MODE == M_SCORE) {
        u16* E = (u16*)Cv + (size_t)bz * sCb;
        float rs[NI][4];
        #pragma unroll
        for (int i = 0; i < NI; ++i)
            #pragma unroll
            for (int g = 0; g < 4; ++g) rs[i][g] = 0.f;
        #pragma unroll
        for (int i = 0; i < NI; ++i)
            #pragma unroll
            for (int j = 0; j < 4; ++j) {
                const int r0 = rowA0 + wm * (TBM / 2) + i * 16 + quad * 4;
                const int c  = rowB0 + wn * 64 + j * 16 + lm;
                #pragma unroll
                for (int g = 0; g < 4; ++g) {
                    const int r = r0 + g;
                    float e = (c <= r) ? exp2f(acc[i][j][g] * kfac) : 0.f;
                    E[(size_t)r * N + c] = f2bf(e);
                    rs[i][g] += e;
                }
            }
        #pragma unroll
        for (int i = 0; i < NI; ++i)
            #pragma unroll
            for (int g = 0; g < 4; ++g) {
                float v = rs[i][g];
                v += __shfl_xor(v, 1); v += __shfl_xor(v, 2);
                v += __shfl_xor(v, 4); v += __shfl_xor(v, 8);
                rs[i][g] = v;
            }
        if (lm == 0) {
            #pragma unroll
            for (int i = 0; i < NI; ++i)
                #pragma unroll
                for (int g = 0; g < 4; ++g) {
                    const int r = rowA0 + wm * (TBM / 2) + i * 16 + quad * 4 + g;
                    atomicAdd(&rowsum[(size_t)bz * M + r], rs[i][g]);
                }
        }
    } else {  // M_PV
        float* C = (float*)Cv + (size_t)bz * sCb;
        #pragma unroll
        for (int i = 0; i < NI; ++i) {
            const int r0 = rowA0 + wm * (TBM / 2) + i * 16 + quad * 4;
            float inv[4];
            #pragma unroll
            for (int g = 0; g < 4; ++g)
                inv[g] = 1.f / rowsum[(size_t)bz * M + r0 + g];
            #pragma unroll
            for (int j = 0; j < 4; ++j) {
                const int c0 = rowB0 + wn * 64 + j * 16 + lm;
                #pragma unroll
                for (int g = 0; g < 4; ++g)
                    C[(size_t)(r0 + g) * N + c0] = acc[i][j][g] * inv[g];
            }
        }
    }
}

// x fp32 -> bf16, 8 elems/thread
__global__ __launch_bounds__(256)
void cast_x(const float* __restrict__ x, u16* __restrict__ o, long long n)
{
    long long i = ((long long)blockIdx.x * blockDim.x + threadIdx.x) * 8;
    if (i >= n) return;
    const float4 a = *(const float4*)(x + i);
    const float4 b = *(const float4*)(x + i + 4);
    union { u16 u[8]; float4 v; } r;
    r.u[0] = f2bf(a.x); r.u[1] = f2bf(a.y); r.u[2] = f2bf(a.z); r.u[3] = f2bf(a.w);
    r.u[4] = f2bf(b.x); r.u[5] = f2bf(b.y); r.u[6] = f2bf(b.z); r.u[7] = f2bf(b.w);
    *(float4*)(o + i) = r.v;
}

// W[z][D][D] fp32 -> Wt[z][D][D] bf16 transposed; z selects Wq/Wk/Wv
__global__ __launch_bounds__(256)
void castT_w3(const float* __restrict__ W0, const float* __restrict__ W1,
              const float* __restrict__ W2, u16* __restrict__ Wt, int D)
{
    const float* W = blockIdx.z == 0 ? W0 : (blockIdx.z == 1 ? W1 : W2);
    u16* dst = Wt + (size_t)blockIdx.z * D * D;
    __shared__ u16 t[32][33];
    const int c0 = blockIdx.x * 32, r0 = blockIdx.y * 32;
    const int tx = threadIdx.x & 31, ty = threadIdx.x >> 5;  // ty 0..7
    #pragma unroll
    for (int s = 0; s < 32; s += 8)
        t[ty + s][tx] = f2bf(W[(size_t)(r0 + ty + s) * D + c0 + tx]);
    __syncthreads();
    #pragma unroll
    for (int s = 0; s < 32; s += 8)
        dst[(size_t)(c0 + ty + s) * D + r0 + tx] = t[tx][ty + s];
}

// V[rows][cols] bf16 -> Vt[cols][rows] bf16, batched via blockIdx.z
__global__ __launch_bounds__(256)
void transpose_b(const u16* __restrict__ V, long long sVb,
                 u16* __restrict__ Vt, long long sVtb, int rows, int cols)
{
    V  += (size_t)blockIdx.z * sVb;
    Vt += (size_t)blockIdx.z * sVtb;
    __shared__ u16 t[32][33];
    const int c0 = blockIdx.x * 32, r0 = blockIdx.y * 32;
    const int tx = threadIdx.x & 31, ty = threadIdx.x >> 5;
    #pragma unroll
    for (int s = 0; s < 32; s += 8)
        t[ty + s][tx] = V[(size_t)(r0 + ty + s) * cols + c0 + tx];
    __syncthreads();
    #pragma unroll
    for (int s = 0; s < 32; s += 8)
        Vt[(size_t)(c0 + ty + s) * rows + r0 + tx] = t[tx][ty + s];
}

extern "C" void kernel_launch(void* const* d_in, const int* in_sizes, int n_in,
                              void* d_out, int out_size, void* d_ws, size_t ws_size,
                              hipStream_t stream)
{
    const int B = 4, T = 2048, D = 1024;
    const float* x  = (const float*)d_in[0];
    const float* Wq = (const float*)d_in[1];
    const float* Wk = (const float*)d_in[2];
    const float* Wv = (const float*)d_in[3];
    float* out = (float*)d_out;

    const size_t nX = (size_t)B * T * D;
    u16* Xb = (u16*)d_ws;                          // [B*T, D] bf16
    u16* Wt = Xb + nX;                             // 3 x [D, D] bf16 transposed
    u16* Q  = Wt + 3 * (size_t)D * D;              // [B*T, D]  (Q,K,V contiguous)
    u16* Kb = Q + nX;
    u16* Vb = Kb + nX;
    u16* Vt = Vb + nX;                             // [B][D][T]
    char* rest = (char*)(Vt + nX);
    const size_t fixed   = (size_t)((char*)rest - (char*)d_ws);
    const size_t perb_E  = (size_t)T * T * 2;
    const size_t perb_rs = (size_t)T * 4;
    const bool full = ws_size >= fixed + (size_t)B * (perb_E + perb_rs);
    const int nb = full ? B : 1;
    u16*   E  = (u16*)rest;
    float* RS = (float*)(E + nb * (size_t)T * T);

    const float kfac = 1.4426950408889634f / 32.0f;  // log2(e)/sqrt(d_out)
    const int nTri64 = 272;   // sum_{bm=0..31} (bm/2 + 1), 64-row tri tiles

    // RS zero first so it overlaps the cast kernels (graph runs in order)
    hipMemsetAsync(RS, 0, (size_t)nb * T * 4, stream);

    // 1. casts
    cast_x<<<dim3((unsigned)(nX / (8 * 256))), 256, 0, stream>>>(x, Xb, (long long)nX);
    castT_w3<<<dim3(D / 32, D / 32, 3), 256, 0, stream>>>(Wq, Wk, Wv, Wt, D);

    // 2. Merged QKV projection (128x128, KB=64: measured 805 TF / 64 us)
    gemm_bt<M_QKV, 128><<<dim3(3 * D / 128, (B * T) / 128, 1), 256, 0, stream>>>(
        Xb, 0, Wt, 0, Q, (long long)nX, nullptr, B * T, 3 * D, D, 0.f);

    if (full) {
        // 3. E = exp2(kfac * Q K^T) bf16 (causal) + rowsum; 64x128 tiles,
        //    1088 blocks (~4.25/CU residency at 24 KB LDS)
        gemm_bt<M_SCORE, 64><<<dim3(nTri64, 1, B), 256, 0, stream>>>(
            Q, (long long)T * D, Kb, (long long)T * D, E, (long long)T * T, RS,
            T, T, D, kfac);
        // 4. V^T
        transpose_b<<<dim3(D / 32, T / 32, B), 256, 0, stream>>>(
            Vb, (long long)T * D, Vt, (long long)D * T, T, D);
        // 5. O = (E Vt^T) / rowsum; 64x128 tiles, 1024 blocks, causal K-loop
        gemm_bt<M_PV, 64><<<dim3(D / 128, T / 64, B), 256, 0, stream>>>(
            E, (long long)T * T, Vt, (long long)D * T, out, (long long)T * D, RS,
            T, D, T, 0.f);
    } else {
        for (int b = 0; b < B; ++b) {
            const size_t ob = (size_t)b * T * D;
            if (b) hipMemsetAsync(RS, 0, (size_t)T * 4, stream);
            gemm_bt<M_SCORE, 64><<<dim3(nTri64, 1, 1), 256, 0, stream>>>(
                Q + ob, 0, Kb + ob, 0, E, 0, RS, T, T, D, kfac);
            transpose_b<<<dim3(D / 32, T / 32, 1), 256, 0, stream>>>(
                Vb + ob, 0, Vt, 0, T, D);
            gemm_bt<M_PV, 64><<<dim3(D / 128, T / 64, 1), 256, 0, stream>>>(
                E, 0, Vt, 0, out + ob, 0, RS, T, D, T, 0.f);
        }
    }
}

// Round 8
// 246.190 us; speedup vs baseline: 1.0277x; 1.0048x over previous
//
#include <hip/hip_runtime.h>
#include <stdint.h>
#include <math.h>

typedef unsigned short u16;
typedef __bf16 bf16x8 __attribute__((ext_vector_type(8)));
typedef float f32x4 __attribute__((ext_vector_type(4)));

enum { M_QKV = 0, M_SCORE = 1, M_PV = 2 };

// fp32 -> bf16 round-to-nearest-even, bit-level
__device__ __forceinline__ u16 f2bf(float f) {
    union { float f; unsigned int u; } a; a.f = f;
    unsigned int u = a.u;
    u += 0x7FFFu + ((u >> 16) & 1u);
    return (u16)(u >> 16);
}

__device__ __forceinline__ void async_load16(const void* g, void* l) {
    __builtin_amdgcn_global_load_lds(
        (const __attribute__((address_space(1))) void*)g,
        (__attribute__((address_space(3))) void*)l,
        16, 0, 0);
}

// ---------------------------------------------------------------------------
// Shared GEMM core (bf16 in, fp32 acc), TBM x 128 tile, KB=64/iter, 4 waves
// 2x2. LDS granule (row,g) at slot g^(row&7); staging permutes the *global*
// granule per lane (R3/R5-verified family: 0 bank conflicts).
// ---------------------------------------------------------------------------
template<int MODE, int TBM>
__device__ __forceinline__ void gemm_core(
    const u16* __restrict__ A, const u16* __restrict__ Bt,
    void* __restrict__ Cv, float* __restrict__ rowsum,
    int bm, int bn, int bz, int M, int N, int K, float kfac,
    u16* As, u16* Bs)
{
    constexpr int KB  = 64;
    constexpr int NI  = TBM / 32;        // m-frags per wave
    constexpr int ACH = TBM / 32;        // A staging chunks per wave
    constexpr int BCH = 4;               // B staging chunks per wave

    const int tid  = threadIdx.x;
    const int lane = tid & 63;
    const int wv   = tid >> 6;
    const int wm   = wv >> 1;
    const int wn   = wv & 1;

    f32x4 acc[NI][4] = {};

    const int rowA0 = bm * TBM, rowB0 = bn * 128;
    const int lrow  = lane >> 3;
    const int lslot = lane & 7;
    const int sg    = (lslot ^ lrow) * 8;

    int kEnd = K;
    if (MODE == M_PV) { int ke = (bm + 1) * TBM; kEnd = ke < K ? ke : K; }

    const int lm   = lane & 15;
    const int quad = lane >> 4;
    const int rx   = lm & 7;

    for (int k0 = 0; k0 < kEnd; k0 += KB) {
        #pragma unroll
        for (int c = 0; c < ACH; ++c) {
            const int cc  = wv * ACH + c;
            const int row = cc * 8 + lrow;
            async_load16(&A[(size_t)(rowA0 + row) * K + k0 + sg], &As[cc * 512 + lane * 8]);
        }
        #pragma unroll
        for (int c = 0; c < BCH; ++c) {
            const int cc  = wv * BCH + c;
            const int row = cc * 8 + lrow;
            async_load16(&Bt[(size_t)(rowB0 + row) * K + k0 + sg], &Bs[cc * 512 + lane * 8]);
        }
        __syncthreads();

        #pragma unroll
        for (int h = 0; h < 2; ++h) {
            const int sl = (((h * 4 + quad) ^ rx) * 8);
            bf16x8 af[NI], bfr[4];
            #pragma unroll
            for (int i = 0; i < NI; ++i)
                af[i] = *reinterpret_cast<const bf16x8*>(
                    &As[(wm * (TBM / 2) + i * 16 + lm) * KB + sl]);
            #pragma unroll
            for (int j = 0; j < 4; ++j)
                bfr[j] = *reinterpret_cast<const bf16x8*>(
                    &Bs[(wn * 64 + j * 16 + lm) * KB + sl]);
            #pragma unroll
            for (int i = 0; i < NI; ++i)
                #pragma unroll
                for (int j = 0; j < 4; ++j)
                    acc[i][j] = __builtin_amdgcn_mfma_f32_16x16x32_bf16(af[i], bfr[j], acc[i][j], 0, 0, 0);
        }
        __syncthreads();
    }

    // Epilogue. C/D layout (m89-verified): col = lane&15, row = quad*4 + reg.
    if (MODE == M_QKV) {
        u16* C = (u16*)Cv + (size_t)(bn >> 3) * ((size_t)M * 1024);  // 0-7:Q,8-15:K,16-23:V
        #pragma unroll
        for (int i = 0; i < NI; ++i)
            #pragma unroll
            for (int j = 0; j < 4; ++j) {
                const int r0 = rowA0 + wm * (TBM / 2) + i * 16 + quad * 4;
                const int c0 = (rowB0 + wn * 64 + j * 16 + lm) & 1023;
                #pragma unroll
                for (int g = 0; g < 4; ++g)
                    C[(size_t)(r0 + g) * 1024 + c0] = f2bf(acc[i][j][g]);
            }
    } else if (MODE == M_SCORE) {
        u16* E = (u16*)Cv + (size_t)bz * ((size_t)M * N);
        float rs[NI][4];
        #pragma unroll
        for (int i = 0; i < NI; ++i)
            #pragma unroll
            for (int g = 0; g < 4; ++g) rs[i][g] = 0.f;
        #pragma unroll
        for (int i = 0; i < NI; ++i)
            #pragma unroll
            for (int j = 0; j < 4; ++j) {
                const int r0 = rowA0 + wm * (TBM / 2) + i * 16 + quad * 4;
                const int c  = rowB0 + wn * 64 + j * 16 + lm;
                #pragma unroll
                for (int g = 0; g < 4; ++g) {
                    const int r = r0 + g;
                    float e = (c <= r) ? exp2f(acc[i][j][g] * kfac) : 0.f;
                    E[(size_t)r * N + c] = f2bf(e);
                    rs[i][g] += e;
                }
            }
        #pragma unroll
        for (int i = 0; i < NI; ++i)
            #pragma unroll
            for (int g = 0; g < 4; ++g) {
                float v = rs[i][g];
                v += __shfl_xor(v, 1); v += __shfl_xor(v, 2);
                v += __shfl_xor(v, 4); v += __shfl_xor(v, 8);
                rs[i][g] = v;
            }
        if (lm == 0) {
            #pragma unroll
            for (int i = 0; i < NI; ++i)
                #pragma unroll
                for (int g = 0; g < 4; ++g) {
                    const int r = rowA0 + wm * (TBM / 2) + i * 16 + quad * 4 + g;
                    atomicAdd(&rowsum[(size_t)bz * M + r], rs[i][g]);
                }
        }
    } else {  // M_PV
        float* C = (float*)Cv + (size_t)bz * ((size_t)M * N);
        #pragma unroll
        for (int i = 0; i < NI; ++i) {
            const int r0 = rowA0 + wm * (TBM / 2) + i * 16 + quad * 4;
            float inv[4];
            #pragma unroll
            for (int g = 0; g < 4; ++g)
                inv[g] = 1.f / rowsum[(size_t)bz * M + r0 + g];
            #pragma unroll
            for (int j = 0; j < 4; ++j) {
                const int c0 = rowB0 + wn * 64 + j * 16 + lm;
                #pragma unroll
                for (int g = 0; g < 4; ++g)
                    C[(size_t)(r0 + g) * N + c0] = acc[i][j][g] * inv[g];
            }
        }
    }
}

// QKV: 128x128 tiles, row-major Q|K|V out
__global__ __launch_bounds__(256)
void k_qkv(const u16* __restrict__ Xb, const u16* __restrict__ Wt,
           u16* __restrict__ Q, int M, int N, int K)
{
    __shared__ __attribute__((aligned(16))) u16 As[128 * 64];
    __shared__ __attribute__((aligned(16))) u16 Bs[128 * 64];
    gemm_core<M_QKV, 128>(Xb, Wt, Q, nullptr, blockIdx.y, blockIdx.x, 0,
                          M, N, K, 0.f, As, Bs);
}

// S (tri 64x128 blocks) + V-transpose (trailing blocks fill the tail).
// Blocks [0, nTri): E = exp2(kfac * Q K^T) causal + rowsum.
// Blocks [nTri, nTri+2048): 32x32 transpose tiles of V -> Vt[b][c][t].
__global__ __launch_bounds__(256)
void k_score_vt(const u16* __restrict__ Q, const u16* __restrict__ Kb,
                u16* __restrict__ E, float* __restrict__ rowsum,
                const u16* __restrict__ Vb, u16* __restrict__ Vt,
                int T, int D, float kfac, int nTri)
{
    __shared__ __attribute__((aligned(16))) u16 As[64 * 64];
    __shared__ __attribute__((aligned(16))) u16 Bs[128 * 64];
    __shared__ u16 tt[32][33];
    const int bz = blockIdx.z;

    if ((int)blockIdx.x < nTri) {
        // 64-row tri decode (verified R4)
        const int idx = blockIdx.x;
        int w = (int)sqrtf((float)idx + 0.5f);
        while (w * w > idx) --w;
        while ((w + 1) * (w + 1) <= idx) ++w;
        int bm, bn;
        if (idx < w * w + w) { bm = 2 * w - 1; bn = idx - w * w; }
        else                 { bm = 2 * w;     bn = idx - (w * w + w); }
        gemm_core<M_SCORE, 64>(Q + (size_t)bz * T * D, Kb + (size_t)bz * T * D,
                               E, rowsum, bm, bn, bz, T, T, D, kfac, As, Bs);
    } else {
        const int t  = blockIdx.x - nTri;
        const int cx = t & 31;          // D/32 tiles
        const int cy = t >> 5;          // T/32 tiles
        const u16* V = Vb + (size_t)bz * T * D;
        u16*      Vo = Vt + (size_t)bz * D * T;
        const int c0 = cx * 32, r0 = cy * 32;
        const int tx = threadIdx.x & 31, ty = threadIdx.x >> 5;
        #pragma unroll
        for (int s = 0; s < 32; s += 8)
            tt[ty + s][tx] = V[(size_t)(r0 + ty + s) * D + c0 + tx];
        __syncthreads();
        #pragma unroll
        for (int s = 0; s < 32; s += 8)
            Vo[(size_t)(c0 + ty + s) * T + r0 + tx] = tt[tx][ty + s];
    }
}

// PV: 64x128 tiles, heavy rows (large bm) dispatched FIRST (LPT scheduling)
__global__ __launch_bounds__(256)
void k_pv(const u16* __restrict__ E, const u16* __restrict__ Vt,
          float* __restrict__ out, const float* __restrict__ rowsum,
          int T, int D)
{
    __shared__ __attribute__((aligned(16))) u16 As[64 * 64];
    __shared__ __attribute__((aligned(16))) u16 Bs[128 * 64];
    const int bz = blockIdx.z;
    const int bm = (gridDim.y - 1) - blockIdx.y;   // heavy-first
    gemm_core<M_PV, 64>(E + (size_t)bz * T * T, Vt + (size_t)bz * D * T,
                        out, (float*)rowsum, bm, blockIdx.x, bz,
                        T, D, T, 0.f, As, Bs);
}

// prep: cast_x (blocks [0,nCX)) + W transpose-cast ([nCX,nCX+nW)) + RS zero
__global__ __launch_bounds__(256)
void k_prep(const float* __restrict__ x,
            const float* __restrict__ W0, const float* __restrict__ W1,
            const float* __restrict__ W2,
            u16* __restrict__ Xb, u16* __restrict__ Wt, float* __restrict__ RS,
            int D, int nCX, int nW)
{
    const int bx = blockIdx.x;
    if (bx < nCX) {
        long long i = ((long long)bx * 256 + threadIdx.x) * 8;
        const float4 a = *(const float4*)(x + i);
        const float4 b = *(const float4*)(x + i + 4);
        union { u16 u[8]; float4 v; } r;
        r.u[0] = f2bf(a.x); r.u[1] = f2bf(a.y); r.u[2] = f2bf(a.z); r.u[3] = f2bf(a.w);
        r.u[4] = f2bf(b.x); r.u[5] = f2bf(b.y); r.u[6] = f2bf(b.z); r.u[7] = f2bf(b.w);
        *(float4*)(Xb + i) = r.v;
    } else if (bx < nCX + nW) {
        __shared__ u16 t[32][33];
        const int w  = bx - nCX;
        const int z  = w >> 10;                 // 1024 tiles per matrix (32x32)
        const int rm = w & 1023;
        const float* W = z == 0 ? W0 : (z == 1 ? W1 : W2);
        u16* dst = Wt + (size_t)z * D * D;
        const int c0 = (rm & 31) * 32, r0 = (rm >> 5) * 32;
        const int tx = threadIdx.x & 31, ty = threadIdx.x >> 5;
        #pragma unroll
        for (int s = 0; s < 32; s += 8)
            t[ty + s][tx] = f2bf(W[(size_t)(r0 + ty + s) * D + c0 + tx]);
        __syncthreads();
        #pragma unroll
        for (int s = 0; s < 32; s += 8)
            dst[(size_t)(c0 + ty + s) * D + r0 + tx] = t[tx][ty + s];
    } else {
        const int t = bx - nCX - nW;
        ((float4*)RS)[t * 256 + threadIdx.x] = float4{0.f, 0.f, 0.f, 0.f};
    }
}

extern "C" void kernel_launch(void* const* d_in, const int* in_sizes, int n_in,
                              void* d_out, int out_size, void* d_ws, size_t ws_size,
                              hipStream_t stream)
{
    const int B = 4, T = 2048, D = 1024;
    const float* x  = (const float*)d_in[0];
    const float* Wq = (const float*)d_in[1];
    const float* Wk = (const float*)d_in[2];
    const float* Wv = (const float*)d_in[3];
    float* out = (float*)d_out;

    const size_t nX = (size_t)B * T * D;
    u16* Xb = (u16*)d_ws;                          // [B*T, D] bf16
    u16* Wt = Xb + nX;                             // 3 x [D, D] bf16 transposed
    u16* Q  = Wt + 3 * (size_t)D * D;              // [B*T, D]  (Q,K,V contiguous)
    u16* Kb = Q + nX;
    u16* Vb = Kb + nX;
    u16* Vt = Vb + nX;                             // [B][D][T]
    char* rest = (char*)(Vt + nX);
    const size_t fixed   = (size_t)((char*)rest - (char*)d_ws);
    const size_t perb_E  = (size_t)T * T * 2;
    const size_t perb_rs = (size_t)T * 4;
    const bool full = ws_size >= fixed + (size_t)B * (perb_E + perb_rs);
    const int nb = full ? B : 1;
    u16*   E  = (u16*)rest;
    float* RS = (float*)(E + nb * (size_t)T * T);

    const float kfac = 1.4426950408889634f / 32.0f;  // log2(e)/sqrt(d_out)
    const int nTri64 = 272;   // sum_{bm=0..31} (bm/2 + 1), 64-row tri tiles
    const int nCX = (int)(nX / (8 * 256));           // 4096 cast blocks
    const int nW  = 3 * (D / 32) * (D / 32);         // 3072 W-transpose blocks
    const int nRS = (nb * T) / (4 * 256);            // RS-zero blocks (float4)

    if (full) {
        // 1. prep: x-cast + W-transpose-cast + RS zero, one dispatch
        k_prep<<<dim3(nCX + nW + nRS), 256, 0, stream>>>(
            x, Wq, Wk, Wv, Xb, Wt, RS, D, nCX, nW);
        // 2. merged QKV projection (128x128, KB=64: measured 805 TF / 64 us)
        k_qkv<<<dim3(3 * D / 128, (B * T) / 128), 256, 0, stream>>>(
            Xb, Wt, Q, B * T, 3 * D, D);
        // 3. S (1088 tri blocks) + V-transpose (8192 tail-fill blocks)
        k_score_vt<<<dim3(nTri64 + (D / 32) * (T / 32), 1, B), 256, 0, stream>>>(
            Q, Kb, E, RS, Vb, Vt, T, D, kfac, nTri64);
        // 4. PV, heavy-first
        k_pv<<<dim3(D / 128, T / 64, B), 256, 0, stream>>>(E, Vt, out, RS, T, D);
    } else {
        k_prep<<<dim3(nCX + nW + nRS), 256, 0, stream>>>(
            x, Wq, Wk, Wv, Xb, Wt, RS, D, nCX, nW);
        k_qkv<<<dim3(3 * D / 128, (B * T) / 128), 256, 0, stream>>>(
            Xb, Wt, Q, B * T, 3 * D, D);
        for (int b = 0; b < B; ++b) {
            const size_t ob = (size_t)b * T * D;
            if (b) hipMemsetAsync(RS, 0, (size_t)T * 4, stream);
            k_score_vt<<<dim3(nTri64 + (D / 32) * (T / 32), 1, 1), 256, 0, stream>>>(
                Q + ob, Kb + ob, E, RS, Vb + ob, Vt, T, D, kfac, nTri64);
            k_pv<<<dim3(D / 128, T / 64, 1), 256, 0, stream>>>(
                E, Vt, out + ob, RS, T, D);
        }
    }
}